// Round 10
// baseline (442.845 us; speedup 1.0000x reference)
//
#include <hip/hip_runtime.h>

typedef float f32x4 __attribute__((ext_vector_type(4)));
typedef __bf16 bf16x8 __attribute__((ext_vector_type(8)));
typedef unsigned short u16x8 __attribute__((ext_vector_type(8)));

__device__ __forceinline__ unsigned short f2bf(float f) {
  union { float f; unsigned int u; } v; v.f = f;
  unsigned int u = v.u;
  unsigned int r = (u + 0x7FFFu + ((u >> 16) & 1u)) >> 16;  // RNE
  return (unsigned short)r;
}

// ---------------- cast x (f32 -> bf16), 8 elems/thread, grid-stride ----------------
__global__ __launch_bounds__(256) void k_cast_bf16(const float* __restrict__ in,
                                                   unsigned short* __restrict__ out, int n8) {
  const f32x4* p = (const f32x4*)in;
  for (int i = blockIdx.x * 256 + threadIdx.x; i < n8; i += 2048 * 256) {
    f32x4 a = p[2 * i], b = p[2 * i + 1];
    u16x8 o;
    o[0] = f2bf(a[0]); o[1] = f2bf(a[1]); o[2] = f2bf(a[2]); o[3] = f2bf(a[3]);
    o[4] = f2bf(b[0]); o[5] = f2bf(b[1]); o[6] = f2bf(b[2]); o[7] = f2bf(b[3]);
    ((u16x8*)out)[i] = o;
  }
}

// -------- Bw[o][e*16+r] = coeffs[e]*scales[e]*Bf[e][o][r], bf16 --------
__global__ void k_build_bw(const float* __restrict__ Bf,
                           const float* __restrict__ coeffs,
                           const float* __restrict__ scales,
                           unsigned short* __restrict__ bw) {
  int t = blockIdx.x * 256 + threadIdx.x;
  int o = t >> 8, k = t & 255, e = k >> 4, r = k & 15;
  float v = coeffs[e] * scales[e] * Bf[((size_t)e * 4096 + o) * 16 + r];
  bw[t] = f2bf(v);
}

// -------- At[d][e*16+r] = A[e][r][d], bf16, via LDS transpose --------
__global__ void k_build_at(const float* __restrict__ A,
                           unsigned short* __restrict__ at) {
  __shared__ float tile[64][65];
  int kt = blockIdx.x * 64, dt = blockIdx.y * 64;
  int tx = threadIdx.x & 63, ty = threadIdx.x >> 6;
#pragma unroll
  for (int j = 0; j < 64; j += 4)
    tile[ty + j][tx] = A[(size_t)(kt + ty + j) * 4096 + dt + tx];
  __syncthreads();
#pragma unroll
  for (int j = 0; j < 64; j += 4)
    at[(size_t)(dt + ty + j) * 256 + kt + tx] = f2bf(tile[tx][ty + j]);
}

// ------------- prep GEMM (m97 structure), W_eff = Bw @ At^T + W -------------
template <int M_, int N_, int K_>
__global__ __launch_bounds__(256) void k_gemm_prep(
    const unsigned short* __restrict__ Abuf,
    const unsigned short* __restrict__ Bbuf,
    const float* __restrict__ Wadd,
    unsigned short* __restrict__ outB) {
  constexpr int NBN = N_ / 128;
  constexpr int NWG = (M_ / 128) * NBN;
  const int bid = blockIdx.x;
  const int swz = (bid & 7) * (NWG / 8) + (bid >> 3);
  const int bm = swz / NBN, bn = swz % NBN;

  __shared__ unsigned short ldsA[128 * 64];
  __shared__ unsigned short ldsB[128 * 64];

  const int t = threadIdx.x, w = t >> 6, l = t & 63;
  const int wr = w >> 1, wc = w & 1;

  f32x4 acc[4][4] = {};
  const int m0 = bm * 128, n0 = bn * 128;
  const int srow = w * 8 + (l >> 3);
  const int scol = (l & 7) * 8;
  const unsigned short* gA = Abuf + (size_t)(m0 + srow) * K_ + scol;
  const unsigned short* gB = Bbuf + (size_t)(n0 + srow) * K_ + scol;

  for (int kt = 0; kt < K_; kt += 64) {
#pragma unroll
    for (int i = 0; i < 4; ++i) {
      __builtin_amdgcn_global_load_lds(
          (__attribute__((address_space(1))) void*)(gA + (size_t)i * 32 * K_ + kt),
          (__attribute__((address_space(3))) void*)(ldsA + i * 2048 + w * 512), 16, 0, 0);
      __builtin_amdgcn_global_load_lds(
          (__attribute__((address_space(1))) void*)(gB + (size_t)i * 32 * K_ + kt),
          (__attribute__((address_space(3))) void*)(ldsB + i * 2048 + w * 512), 16, 0, 0);
    }
    __syncthreads();
#pragma unroll
    for (int kk = 0; kk < 2; ++kk) {
      const int col = kk * 32 + (l >> 4) * 8;
      const int arow = wr * 64 + (l & 15);
      const int brow = wc * 64 + (l & 15);
      bf16x8 af[4], bfv[4];
#pragma unroll
      for (int mi = 0; mi < 4; ++mi)
        af[mi] = *(const bf16x8*)&ldsA[(arow + mi * 16) * 64 + col];
#pragma unroll
      for (int ni = 0; ni < 4; ++ni)
        bfv[ni] = *(const bf16x8*)&ldsB[(brow + ni * 16) * 64 + col];
#pragma unroll
      for (int mi = 0; mi < 4; ++mi)
#pragma unroll
        for (int ni = 0; ni < 4; ++ni)
          acc[mi][ni] = __builtin_amdgcn_mfma_f32_16x16x32_bf16(
              af[mi], bfv[ni], acc[mi][ni], 0, 0, 0);
    }
    __syncthreads();
  }

  const int mrow0 = m0 + wr * 64 + (l >> 4) * 4;
  const int ncol0 = n0 + wc * 64 + (l & 15);
#pragma unroll
  for (int mi = 0; mi < 4; ++mi)
#pragma unroll
    for (int r = 0; r < 4; ++r) {
      const int m = mrow0 + mi * 16 + r;
#pragma unroll
      for (int ni = 0; ni < 4; ++ni) {
        const int n = ncol0 + ni * 16;
        outB[(size_t)m * N_ + n] = f2bf(acc[mi][ni][r] + Wadd[(size_t)m * N_ + n]);
      }
    }
}

// ===== main GEMM: 256x256, BK=32, A via LDS ring-5, B DIRECT from global =====
// out f32 = A*B^T + bias.  A [M_][K_] bf16 staged via global_load_lds with
// the proven XOR swizzle (phys slot s at row r holds block s^((r>>1)&3);
// global source pre-swizzled, rule #21).  B [N_][K_] bf16 fragments loaded
// STRAIGHT from global (weff is 32 MiB -> L2/L3 resident) via inline-asm
// global_load_dwordx4 into 4 register sets (tile mod 4), 4 tiles ahead.
// All in-loop VMEM is asm/builtin -> exact manual vmcnt accounting:
// per-iter issues [B(t+4)x4, Astage(t+3)x2, B(t+5)x4, Astage(t+4)x2];
// top-of-iter wait vmcnt(6) (first iter 10, last 0) proves tiles t,t+1
// fully available (A in LDS + B in regs).  LDS pipe/iter drops ~2800->~1800
// cyc (8 ds_read/tile instead of 12; half the staging writes).
template <int M_, int N_, int K_>
__global__ __launch_bounds__(512, 2) void k_gemm256(
    const unsigned short* __restrict__ Abuf,
    const unsigned short* __restrict__ Bbuf,
    const float* __restrict__ bias,
    float* __restrict__ outF) {
  constexpr int NBN = N_ / 256;
  constexpr int NWG = (M_ / 256) * NBN;
  constexpr int NT = K_ / 32;
  static_assert(NWG % 8 == 0, "bijective xcd swizzle");
  static_assert(NT % 4 == 0 && NT >= 8, "pipeline depth");

  const int bid = blockIdx.x;
  const int swz = (bid & 7) * (NWG / 8) + (bid >> 3);
  const int bm = swz / NBN, bn = swz % NBN;
  const int m0 = bm * 256, n0 = bn * 256;

  __shared__ __attribute__((aligned(128))) unsigned short lds[40960];  // 80 KiB = 5 x 16 KiB
  char* ldsb = (char*)lds;

  const int tid = threadIdx.x, w = tid >> 6, l = tid & 63;
  const int wr = w >> 2, wc = w & 3;  // 2 M-waves x 4 N-waves; per-wave 128x64

  // A staging: instr i covers rows i*128 + w*16 + (l>>2); dest linear lane*16
  const int scol = ((l & 3) ^ ((l >> 3) & 3)) * 8;
  const unsigned short* gA = Abuf + (size_t)(m0 + w * 16 + (l >> 2)) * K_ + scol;
  const int dA = w * 1024;  // + buf*16384 + i*8192

  // A fragment reads: row = base + (l&15); phys slot = (l>>4) ^ ((row>>1)&3)
  const int qp = ((l >> 4) ^ ((l >> 1) & 3)) << 4;
  const int raOff = (wr * 128 + (l & 15)) * 64 + qp;  // + mi*1024 + buf*16384

  // B fragment global bases (per ni): row = n0 + wc*64 + ni*16 + (l&15),
  // col = (l>>4)*8; tile t adds t*64 bytes.
  const unsigned long long bB0 =
      (unsigned long long)(uintptr_t)Bbuf +
      2ull * ((unsigned long long)(n0 + wc * 64 + (l & 15)) * K_ + ((l >> 4) * 8));
  const unsigned long long niStep = (unsigned long long)16 * K_ * 2;
  const unsigned long long bB1 = bB0 + niStep;
  const unsigned long long bB2 = bB0 + 2 * niStep;
  const unsigned long long bB3 = bB0 + 3 * niStep;

  f32x4 acc[8][4] = {};
  bf16x8 bs0[4], bs1[4], bs2[4], bs3[4];  // B reg sets, tile mod 4

#define GLB(dst, base, toff)                                              \
  asm volatile("global_load_dwordx4 %0, %1, off"                         \
               : "=v"(dst)                                                \
               : "v"((base) + (unsigned long long)(unsigned)(toff))       \
               : "memory")
#define LOADB(S, toff)                                                    \
  do {                                                                    \
    GLB(S[0], bB0, toff); GLB(S[1], bB1, toff);                           \
    GLB(S[2], bB2, toff); GLB(S[3], bB3, toff);                           \
  } while (0)

#define STAGE_A(tt, bf)                                                                \
  do {                                                                                 \
    const int bb_ = (bf) * 16384;                                                      \
    const size_t ko_ = (size_t)(tt) * 32;                                              \
    _Pragma("unroll") for (int i_ = 0; i_ < 2; ++i_) {                                 \
      __builtin_amdgcn_global_load_lds(                                                \
          (__attribute__((address_space(1))) void*)(gA + (size_t)i_ * 128 * K_ + ko_), \
          (__attribute__((address_space(3))) void*)(ldsb + bb_ + i_ * 8192 + dA),      \
          16, 0, 0);                                                                   \
    }                                                                                  \
  } while (0)

#define RD_A(mi, bf) (*(const bf16x8*)(ldsb + (bf) * 16384 + raOff + (mi) * 1024))

// one K-tile: 8 ds_read_b128 (A) -> 32 MFMA with B reg set S
#define TILE(bf, S)                                                                     \
  do {                                                                                  \
    bf16x8 fa0 = RD_A(0, bf), fa1 = RD_A(1, bf), fa2 = RD_A(2, bf), fa3 = RD_A(3, bf);  \
    bf16x8 fa4 = RD_A(4, bf), fa5 = RD_A(5, bf), fa6 = RD_A(6, bf), fa7 = RD_A(7, bf);  \
    __builtin_amdgcn_s_setprio(1);                                                      \
    _Pragma("unroll") for (int ni_ = 0; ni_ < 4; ++ni_) {                               \
      acc[0][ni_] = __builtin_amdgcn_mfma_f32_16x16x32_bf16(fa0, S[ni_], acc[0][ni_], 0, 0, 0); \
      acc[1][ni_] = __builtin_amdgcn_mfma_f32_16x16x32_bf16(fa1, S[ni_], acc[1][ni_], 0, 0, 0); \
      acc[2][ni_] = __builtin_amdgcn_mfma_f32_16x16x32_bf16(fa2, S[ni_], acc[2][ni_], 0, 0, 0); \
      acc[3][ni_] = __builtin_amdgcn_mfma_f32_16x16x32_bf16(fa3, S[ni_], acc[3][ni_], 0, 0, 0); \
      acc[4][ni_] = __builtin_amdgcn_mfma_f32_16x16x32_bf16(fa4, S[ni_], acc[4][ni_], 0, 0, 0); \
      acc[5][ni_] = __builtin_amdgcn_mfma_f32_16x16x32_bf16(fa5, S[ni_], acc[5][ni_], 0, 0, 0); \
      acc[6][ni_] = __builtin_amdgcn_mfma_f32_16x16x32_bf16(fa6, S[ni_], acc[6][ni_], 0, 0, 0); \
      acc[7][ni_] = __builtin_amdgcn_mfma_f32_16x16x32_bf16(fa7, S[ni_], acc[7][ni_], 0, 0, 0); \
    }                                                                                   \
    __builtin_amdgcn_s_setprio(0);                                                      \
  } while (0)

#define TOPWAIT(n)                                                        \
  do {                                                                    \
    __builtin_amdgcn_sched_barrier(0);                                    \
    asm volatile("s_waitcnt vmcnt(" #n ")" ::: "memory");                 \
    __builtin_amdgcn_s_barrier();                                         \
    __builtin_amdgcn_sched_barrier(0);                                    \
  } while (0)

  // prologue: [B0 B1 A0 A1 B2 A2 B3] = 22 VMEM ops in flight
  LOADB(bs0, 0);
  LOADB(bs1, 64);
  STAGE_A(0, 0);
  STAGE_A(1, 1);
  LOADB(bs2, 128);
  STAGE_A(2, 2);
  LOADB(bs3, 192);

  int bT = 0;  // LDS buf of tile T0 (= 4b mod 5)
  for (int b = 0; b < NT / 4; ++b) {
    const int T0 = 4 * b;
    const int b1 = (bT + 1 >= 5) ? bT + 1 - 5 : bT + 1;
    const int b2 = (bT + 2 >= 5) ? bT + 2 - 5 : bT + 2;
    const int b3 = (bT + 3 >= 5) ? bT + 3 - 5 : bT + 3;
    const int b4 = (bT + 4 >= 5) ? bT + 4 - 5 : bT + 4;

    // ======== iter A: tiles T0, T0+1 (B sets 0,1) ========
    if (T0 == 0) TOPWAIT(10);
    else         TOPWAIT(6);

    TILE(bT, bs0);
    if (T0 + 4 < NT) LOADB(bs0, (T0 + 4) * 64);   // I1
    if (T0 + 3 < NT) STAGE_A(T0 + 3, b3);         // I2
    TILE(b1, bs1);
    if (T0 + 5 < NT) LOADB(bs1, (T0 + 5) * 64);   // I3
    if (T0 + 4 < NT) STAGE_A(T0 + 4, b4);         // I4

    // ======== iter B: tiles T0+2, T0+3 (B sets 2,3) ========
    if (T0 + 4 < NT) TOPWAIT(6);
    else             TOPWAIT(0);

    TILE(b2, bs2);
    if (T0 + 6 < NT) LOADB(bs2, (T0 + 6) * 64);
    if (T0 + 5 < NT) STAGE_A(T0 + 5, bT);
    TILE(b3, bs3);
    if (T0 + 7 < NT) LOADB(bs3, (T0 + 7) * 64);
    if (T0 + 6 < NT) STAGE_A(T0 + 6, b1);

    bT = (bT + 4 >= 5) ? bT + 4 - 5 : bT + 4;
  }
#undef GLB
#undef LOADB
#undef STAGE_A
#undef RD_A
#undef TILE
#undef TOPWAIT

  // epilogue: C/D layout col = lane&15, row = (lane>>4)*4 + reg
#pragma unroll
  for (int ni = 0; ni < 4; ++ni) {
    const int n = n0 + wc * 64 + ni * 16 + (l & 15);
    const float bv2 = bias[n];
#pragma unroll
    for (int mi = 0; mi < 8; ++mi) {
      const int m = m0 + wr * 128 + mi * 16 + (l >> 4) * 4;
#pragma unroll
      for (int r = 0; r < 4; ++r)
        outF[(size_t)(m + r) * N_ + n] = acc[mi][ni][r] + bv2;
    }
  }
}

extern "C" void kernel_launch(void* const* d_in, const int* in_sizes, int n_in,
                              void* d_out, int out_size, void* d_ws, size_t ws_size,
                              hipStream_t stream) {
  const float* x      = (const float*)d_in[0];
  const float* W      = (const float*)d_in[1];
  const float* bias   = (const float*)d_in[2];
  const float* A      = (const float*)d_in[3];
  const float* Bf     = (const float*)d_in[4];
  const float* coeffs = (const float*)d_in[5];
  const float* scales = (const float*)d_in[6];
  float* out = (float*)d_out;

  char* ws = (char*)d_ws;
  unsigned short* xb   = (unsigned short*)(ws);
  unsigned short* weff = (unsigned short*)(ws + 67108864);
  unsigned short* bw   = (unsigned short*)(ws + 67108864 + 33554432);
  unsigned short* at   = (unsigned short*)(ws + 67108864 + 33554432 + 2097152);

  k_cast_bf16<<<2048, 256, 0, stream>>>(x, xb, (8192 * 4096) / 8);
  k_build_bw<<<4096, 256, 0, stream>>>(Bf, coeffs, scales, bw);
  k_build_at<<<dim3(4, 64), 256, 0, stream>>>(A, at);
  k_gemm_prep<4096, 4096, 256><<<1024, 256, 0, stream>>>(bw, at, W, weff);
  k_gemm256<8192, 4096, 4096><<<512, 512, 0, stream>>>(xb, weff, bias, out);
}

// Round 11
// 346.030 us; speedup vs baseline: 1.2798x; 1.2798x over previous
//
#include <hip/hip_runtime.h>

typedef float f32x4 __attribute__((ext_vector_type(4)));
typedef __bf16 bf16x8 __attribute__((ext_vector_type(8)));
typedef unsigned short u16x8 __attribute__((ext_vector_type(8)));

__device__ __forceinline__ unsigned short f2bf(float f) {
  union { float f; unsigned int u; } v; v.f = f;
  unsigned int u = v.u;
  unsigned int r = (u + 0x7FFFu + ((u >> 16) & 1u)) >> 16;  // RNE
  return (unsigned short)r;
}

// ---------------- cast x (f32 -> bf16), 8 elems/thread, grid-stride ----------------
__global__ __launch_bounds__(256) void k_cast_bf16(const float* __restrict__ in,
                                                   unsigned short* __restrict__ out, int n8) {
  const f32x4* p = (const f32x4*)in;
  for (int i = blockIdx.x * 256 + threadIdx.x; i < n8; i += 2048 * 256) {
    f32x4 a = p[2 * i], b = p[2 * i + 1];
    u16x8 o;
    o[0] = f2bf(a[0]); o[1] = f2bf(a[1]); o[2] = f2bf(a[2]); o[3] = f2bf(a[3]);
    o[4] = f2bf(b[0]); o[5] = f2bf(b[1]); o[6] = f2bf(b[2]); o[7] = f2bf(b[3]);
    ((u16x8*)out)[i] = o;
  }
}

// -------- Bw[o][e*16+r] = coeffs[e]*scales[e]*Bf[e][o][r], bf16 --------
__global__ void k_build_bw(const float* __restrict__ Bf,
                           const float* __restrict__ coeffs,
                           const float* __restrict__ scales,
                           unsigned short* __restrict__ bw) {
  int t = blockIdx.x * 256 + threadIdx.x;
  int o = t >> 8, k = t & 255, e = k >> 4, r = k & 15;
  float v = coeffs[e] * scales[e] * Bf[((size_t)e * 4096 + o) * 16 + r];
  bw[t] = f2bf(v);
}

// -------- At[d][e*16+r] = A[e][r][d], bf16, via LDS transpose --------
__global__ void k_build_at(const float* __restrict__ A,
                           unsigned short* __restrict__ at) {
  __shared__ float tile[64][65];
  int kt = blockIdx.x * 64, dt = blockIdx.y * 64;
  int tx = threadIdx.x & 63, ty = threadIdx.x >> 6;
#pragma unroll
  for (int j = 0; j < 64; j += 4)
    tile[ty + j][tx] = A[(size_t)(kt + ty + j) * 4096 + dt + tx];
  __syncthreads();
#pragma unroll
  for (int j = 0; j < 64; j += 4)
    at[(size_t)(dt + ty + j) * 256 + kt + tx] = f2bf(tile[tx][ty + j]);
}

// ------------- prep GEMM (m97 structure), W_eff = Bw @ At^T + W -------------
template <int M_, int N_, int K_>
__global__ __launch_bounds__(256) void k_gemm_prep(
    const unsigned short* __restrict__ Abuf,
    const unsigned short* __restrict__ Bbuf,
    const float* __restrict__ Wadd,
    unsigned short* __restrict__ outB) {
  constexpr int NBN = N_ / 128;
  constexpr int NWG = (M_ / 128) * NBN;
  const int bid = blockIdx.x;
  const int swz = (bid & 7) * (NWG / 8) + (bid >> 3);
  const int bm = swz / NBN, bn = swz % NBN;

  __shared__ unsigned short ldsA[128 * 64];
  __shared__ unsigned short ldsB[128 * 64];

  const int t = threadIdx.x, w = t >> 6, l = t & 63;
  const int wr = w >> 1, wc = w & 1;

  f32x4 acc[4][4] = {};
  const int m0 = bm * 128, n0 = bn * 128;
  const int srow = w * 8 + (l >> 3);
  const int scol = (l & 7) * 8;
  const unsigned short* gA = Abuf + (size_t)(m0 + srow) * K_ + scol;
  const unsigned short* gB = Bbuf + (size_t)(n0 + srow) * K_ + scol;

  for (int kt = 0; kt < K_; kt += 64) {
#pragma unroll
    for (int i = 0; i < 4; ++i) {
      __builtin_amdgcn_global_load_lds(
          (__attribute__((address_space(1))) void*)(gA + (size_t)i * 32 * K_ + kt),
          (__attribute__((address_space(3))) void*)(ldsA + i * 2048 + w * 512), 16, 0, 0);
      __builtin_amdgcn_global_load_lds(
          (__attribute__((address_space(1))) void*)(gB + (size_t)i * 32 * K_ + kt),
          (__attribute__((address_space(3))) void*)(ldsB + i * 2048 + w * 512), 16, 0, 0);
    }
    __syncthreads();
#pragma unroll
    for (int kk = 0; kk < 2; ++kk) {
      const int col = kk * 32 + (l >> 4) * 8;
      const int arow = wr * 64 + (l & 15);
      const int brow = wc * 64 + (l & 15);
      bf16x8 af[4], bfv[4];
#pragma unroll
      for (int mi = 0; mi < 4; ++mi)
        af[mi] = *(const bf16x8*)&ldsA[(arow + mi * 16) * 64 + col];
#pragma unroll
      for (int ni = 0; ni < 4; ++ni)
        bfv[ni] = *(const bf16x8*)&ldsB[(brow + ni * 16) * 64 + col];
#pragma unroll
      for (int mi = 0; mi < 4; ++mi)
#pragma unroll
        for (int ni = 0; ni < 4; ++ni)
          acc[mi][ni] = __builtin_amdgcn_mfma_f32_16x16x32_bf16(
              af[mi], bfv[ni], acc[mi][ni], 0, 0, 0);
    }
    __syncthreads();
  }

  const int mrow0 = m0 + wr * 64 + (l >> 4) * 4;
  const int ncol0 = n0 + wc * 64 + (l & 15);
#pragma unroll
  for (int mi = 0; mi < 4; ++mi)
#pragma unroll
    for (int r = 0; r < 4; ++r) {
      const int m = mrow0 + mi * 16 + r;
#pragma unroll
      for (int ni = 0; ni < 4; ++ni) {
        const int n = ncol0 + ni * 16;
        outB[(size_t)m * N_ + n] = f2bf(acc[mi][ni][r] + Wadd[(size_t)m * N_ + n]);
      }
    }
}

// ===== main GEMM: 256x256, BK=32, 5-buf ring, REGISTER-PIPELINED fragments =====
// out f32 = A*B^T + bias.  R6 skeleton (ring-5 LDS, XOR swizzle, vmcnt(4) +
// 1 barrier per 2 K-tiles, stage t+3/t+4) + within-wave software pipeline:
//   alpha(t): 8 ds_reads (A mi0-3 -> faL, B -> fbX/fbY alternating)
//   G2(t-1):  16 MFMA mi4-7 of PREVIOUS tile (pure reg: faH, fbPrev)
//             -> executes while alpha(t)'s reads are in flight (HW overlap)
//   beta(t):  4 ds_reads (A mi4-7 -> faH) + stage
//   G1(t):    16 MFMA mi0-3 (faL, fbCur)
// B frags double-buffered (fbX/fbY) since G2 consumes them one tile late;
// faL/faH single-set (write/consume order audited). sched_barrier(0) at each
// phase boundary pins reads above the MFMA clusters (prevents sinking).
// Reg budget: 64 frag VGPR + addr ~25 + acc 128 AGPR ~= 240 < 256 -> 2 w/SIMD.
template <int M_, int N_, int K_>
__global__ __launch_bounds__(512, 2) void k_gemm256(
    const unsigned short* __restrict__ Abuf,
    const unsigned short* __restrict__ Bbuf,
    const float* __restrict__ bias,
    float* __restrict__ outF) {
  constexpr int NBN = N_ / 256;
  constexpr int NWG = (M_ / 256) * NBN;
  constexpr int NT = K_ / 32;
  static_assert(NWG % 8 == 0, "bijective xcd swizzle");
  static_assert(NT % 2 == 0 && NT >= 8, "pipeline depth");

  const int bid = blockIdx.x;
  const int swz = (bid & 7) * (NWG / 8) + (bid >> 3);
  const int bm = swz / NBN, bn = swz % NBN;
  const int m0 = bm * 256, n0 = bn * 256;

  __shared__ __attribute__((aligned(128))) unsigned short lds[81920];  // 160 KiB
  char* ldsb = (char*)lds;

  const int tid = threadIdx.x, w = tid >> 6, l = tid & 63;
  const int wr = w >> 2, wc = w & 3;  // 2 M-waves x 4 N-waves; per-wave 128x64

  // staging: instr i covers rows i*128 + w*16 + (l>>2); dest linear lane*16
  const int scol = ((l & 3) ^ ((l >> 3) & 3)) * 8;
  const unsigned short* gA = Abuf + (size_t)(m0 + w * 16 + (l >> 2)) * K_ + scol;
  const unsigned short* gB = Bbuf + (size_t)(n0 + w * 16 + (l >> 2)) * K_ + scol;
  const int dA = w * 1024;            // + buf*32768 + i*8192
  const int dB = 16384 + w * 1024;

  // fragment reads: row = base + (l&15); phys slot = (l>>4) ^ ((row>>1)&3)
  const int qp = ((l >> 4) ^ ((l >> 1) & 3)) << 4;
  const int raOff = (wr * 128 + (l & 15)) * 64 + qp;           // + mi*1024
  const int rbOff = 16384 + (wc * 64 + (l & 15)) * 64 + qp;    // + ni*1024

  f32x4 acc[8][4] = {};
  bf16x8 faL[4], faH[4], fbX[4], fbY[4];

#define STAGE_T(tt, bf)                                                               \
  do {                                                                                \
    const int bb_ = (bf) * 32768;                                                     \
    const size_t ko_ = (size_t)(tt) * 32;                                             \
    _Pragma("unroll") for (int i_ = 0; i_ < 2; ++i_) {                                \
      __builtin_amdgcn_global_load_lds(                                               \
          (__attribute__((address_space(1))) void*)(gA + (size_t)i_ * 128 * K_ + ko_),\
          (__attribute__((address_space(3))) void*)(ldsb + bb_ + i_ * 8192 + dA),     \
          16, 0, 0);                                                                  \
      __builtin_amdgcn_global_load_lds(                                               \
          (__attribute__((address_space(1))) void*)(gB + (size_t)i_ * 128 * K_ + ko_),\
          (__attribute__((address_space(3))) void*)(ldsb + bb_ + i_ * 8192 + dB),     \
          16, 0, 0);                                                                  \
    }                                                                                 \
  } while (0)

#define RD_A(mi, bf) (*(const bf16x8*)(ldsb + (bf) * 32768 + raOff + (mi) * 1024))
#define RD_B(ni, bf) (*(const bf16x8*)(ldsb + (bf) * 32768 + rbOff + (ni) * 1024))
#define SB __builtin_amdgcn_sched_barrier(0)

#define ALPHA(bf, FB)                                                                 \
  do {                                                                               \
    faL[0] = RD_A(0, bf); faL[1] = RD_A(1, bf);                                      \
    faL[2] = RD_A(2, bf); faL[3] = RD_A(3, bf);                                      \
    FB[0] = RD_B(0, bf); FB[1] = RD_B(1, bf);                                        \
    FB[2] = RD_B(2, bf); FB[3] = RD_B(3, bf);                                        \
    SB;                                                                              \
  } while (0)

#define BETA(bf, stg_t, stg_b, do_stg)                                               \
  do {                                                                               \
    faH[0] = RD_A(4, bf); faH[1] = RD_A(5, bf);                                      \
    faH[2] = RD_A(6, bf); faH[3] = RD_A(7, bf);                                      \
    if (do_stg) STAGE_T(stg_t, stg_b);                                               \
    SB;                                                                              \
  } while (0)

#define G1(FB)                                                                       \
  do {                                                                               \
    __builtin_amdgcn_s_setprio(1);                                                   \
    _Pragma("unroll") for (int ni_ = 0; ni_ < 4; ++ni_) {                            \
      acc[0][ni_] = __builtin_amdgcn_mfma_f32_16x16x32_bf16(faL[0], FB[ni_], acc[0][ni_], 0, 0, 0); \
      acc[1][ni_] = __builtin_amdgcn_mfma_f32_16x16x32_bf16(faL[1], FB[ni_], acc[1][ni_], 0, 0, 0); \
      acc[2][ni_] = __builtin_amdgcn_mfma_f32_16x16x32_bf16(faL[2], FB[ni_], acc[2][ni_], 0, 0, 0); \
      acc[3][ni_] = __builtin_amdgcn_mfma_f32_16x16x32_bf16(faL[3], FB[ni_], acc[3][ni_], 0, 0, 0); \
    }                                                                                \
    __builtin_amdgcn_s_setprio(0);                                                   \
    SB;                                                                              \
  } while (0)

#define G2(FB)                                                                       \
  do {                                                                               \
    __builtin_amdgcn_s_setprio(1);                                                   \
    _Pragma("unroll") for (int ni_ = 0; ni_ < 4; ++ni_) {                            \
      acc[4][ni_] = __builtin_amdgcn_mfma_f32_16x16x32_bf16(faH[0], FB[ni_], acc[4][ni_], 0, 0, 0); \
      acc[5][ni_] = __builtin_amdgcn_mfma_f32_16x16x32_bf16(faH[1], FB[ni_], acc[5][ni_], 0, 0, 0); \
      acc[6][ni_] = __builtin_amdgcn_mfma_f32_16x16x32_bf16(faH[2], FB[ni_], acc[6][ni_], 0, 0, 0); \
      acc[7][ni_] = __builtin_amdgcn_mfma_f32_16x16x32_bf16(faH[3], FB[ni_], acc[7][ni_], 0, 0, 0); \
    }                                                                                \
    __builtin_amdgcn_s_setprio(0);                                                   \
    SB;                                                                              \
  } while (0)

#define TOPWAIT(cond)                                                                \
  do {                                                                               \
    if (cond) asm volatile("s_waitcnt vmcnt(4)" ::: "memory");                       \
    else      asm volatile("s_waitcnt vmcnt(0)" ::: "memory");                       \
    __builtin_amdgcn_s_barrier();                                                    \
    SB;                                                                              \
  } while (0)

  // prologue: stage tiles 0,1,2 into bufs 0,1,2 (12 loads in flight)
  STAGE_T(0, 0); STAGE_T(1, 1); STAGE_T(2, 2);

  // ---- peeled first iteration: tiles 0,1 (no G2 of previous) ----
  TOPWAIT(2 < NT);
  ALPHA(0, fbX);
  BETA(0, 3, 3, 3 < NT);
  G1(fbX);
  ALPHA(1, fbY);
  G2(fbX);                       // tile 0, mi4-7
  BETA(1, 4, 4, 4 < NT);
  G1(fbY);                       // tile 1, mi0-3

  int bT = 2;  // buf of tile tt (tt % 5)
  for (int tt = 2; tt < NT; tt += 2) {
    const int b0 = bT;
    const int b1 = (bT + 1 >= 5) ? bT + 1 - 5 : bT + 1;
    const int s3 = (bT + 3 >= 5) ? bT + 3 - 5 : bT + 3;
    const int s4 = (bT + 4 >= 5) ? bT + 4 - 5 : bT + 4;

    TOPWAIT(tt + 2 < NT);
    ALPHA(b0, fbX);              // reads tile tt (A lo + B)
    G2(fbY);                     // tile tt-1, mi4-7 (overlaps alpha reads)
    BETA(b0, tt + 3, s3, (tt + 3) < NT);
    G1(fbX);                     // tile tt, mi0-3
    ALPHA(b1, fbY);              // reads tile tt+1
    G2(fbX);                     // tile tt, mi4-7 (overlaps alpha reads)
    BETA(b1, tt + 4, s4, (tt + 4) < NT);
    G1(fbY);                     // tile tt+1, mi0-3

    bT += 2; if (bT >= 5) bT -= 5;
  }
  G2(fbY);                       // tile NT-1, mi4-7
#undef STAGE_T
#undef RD_A
#undef RD_B
#undef SB
#undef ALPHA
#undef BETA
#undef G1
#undef G2
#undef TOPWAIT

  // epilogue: C/D layout col = lane&15, row = (lane>>4)*4 + reg
#pragma unroll
  for (int ni = 0; ni < 4; ++ni) {
    const int n = n0 + wc * 64 + ni * 16 + (l & 15);
    const float bv2 = bias[n];
#pragma unroll
    for (int mi = 0; mi < 8; ++mi) {
      const int m = m0 + wr * 128 + mi * 16 + (l >> 4) * 4;
#pragma unroll
      for (int r = 0; r < 4; ++r)
        outF[(size_t)(m + r) * N_ + n] = acc[mi][ni][r] + bv2;
    }
  }
}

extern "C" void kernel_launch(void* const* d_in, const int* in_sizes, int n_in,
                              void* d_out, int out_size, void* d_ws, size_t ws_size,
                              hipStream_t stream) {
  const float* x      = (const float*)d_in[0];
  const float* W      = (const float*)d_in[1];
  const float* bias   = (const float*)d_in[2];
  const float* A      = (const float*)d_in[3];
  const float* Bf     = (const float*)d_in[4];
  const float* coeffs = (const float*)d_in[5];
  const float* scales = (const float*)d_in[6];
  float* out = (float*)d_out;

  char* ws = (char*)d_ws;
  unsigned short* xb   = (unsigned short*)(ws);
  unsigned short* weff = (unsigned short*)(ws + 67108864);
  unsigned short* bw   = (unsigned short*)(ws + 67108864 + 33554432);
  unsigned short* at   = (unsigned short*)(ws + 67108864 + 33554432 + 2097152);

  k_cast_bf16<<<2048, 256, 0, stream>>>(x, xb, (8192 * 4096) / 8);
  k_build_bw<<<4096, 256, 0, stream>>>(Bf, coeffs, scales, bw);
  k_build_at<<<dim3(4, 64), 256, 0, stream>>>(A, at);
  k_gemm_prep<4096, 4096, 256><<<1024, 256, 0, stream>>>(bw, at, W, weff);
  k_gemm256<8192, 4096, 4096><<<512, 512, 0, stream>>>(xb, weff, bias, out);
}